// Round 5
// baseline (1258.391 us; speedup 1.0000x reference)
//
#include <hip/hip_runtime.h>
#include <hip/hip_bf16.h>

// ---------------------------------------------------------------------------
// RNNCell encoder: seq=512, batch=512, H=IN=300.
//   prep:   W_ih, W_hh -> bf16 zero-padded [320][320]; bias = b_ih+b_hh.
//   xproj:  R8 structure (kept): LDS staging, Bs triple-buffered, counted
//           vmcnt(3)/(2) + lgkm-only barrier; never a vmcnt(0) drain.
//   recur:  R10: 32 WGs x 512 thr x 16 batch (R5 mapping). Proven facts:
//           latency-bound (R9: 2x CUs + half LDS beats = zero gain; R2-R4:
//           huge spills = same step time). Per-SIMD MFMA pipe cost is
//           ~19.4 cy/mfma (MfmaUtil x8 = 36% matches 50x19.4/2635).
//           Step anatomy: ramp ~300 + MFMA ~950 + tanh tail ~600 EXPOSED.
//           R10 hides the tail: K split L(ks0-4)/H(ks5-9) with separate
//           accs (halves dep depth); per-tile H chain followed immediately
//           by that tile's combine+tanh+write so the scheduler sinks tanh j
//           under tile j+1's MFMAs (same-wave cross-pipe co-issue). B-frags
//           register-staged per half (20 VGPR peak). xc folded into L-acc
//           init (adds moved off the tail). Reg audit: 120 AGPR + ~125
//           VGPR <= 256 @ 2 waves/SIMD.
// ---------------------------------------------------------------------------

typedef unsigned short u16;
typedef unsigned int   u32;
typedef __attribute__((ext_vector_type(8)))  short bf16x8;
typedef __attribute__((ext_vector_type(4)))  short s16x4;
typedef __attribute__((ext_vector_type(4)))  float f32x4;
typedef __attribute__((ext_vector_type(16))) float f32x16;
typedef __attribute__((ext_vector_type(2)))  unsigned int u32x2;
typedef __attribute__((ext_vector_type(4)))  unsigned int u32x4;

#define HID 300
#define KP  320
#define SEQ 512
#define BZ  512
#define MTOT (SEQ*BZ)

__device__ __forceinline__ u16 f2bf(float f) {
    u32 u = __float_as_uint(f);
    return (u16)((u + 0x7FFFu + ((u >> 16) & 1u)) >> 16);  // RNE
}
__device__ __forceinline__ float bf2f(u16 h) {
    return __uint_as_float((u32)h << 16);
}
__device__ __forceinline__ float tanh_fast(float x) {
    float e = __builtin_amdgcn_exp2f(x * 2.8853900817779268f);  // exp(2x)
    float r = __builtin_amdgcn_rcpf(e + 1.0f);
    return __builtin_fmaf(-2.0f, r, 1.0f);
}
__device__ __forceinline__ u32 pack2(float a, float b) {
    __hip_bfloat162 t = __float22bfloat162_rn(float2{a, b});  // v_cvt_pk_bf16_f32
    return *(u32*)&t;
}
// Workgroup barrier WITHOUT vmcnt drain: LDS ordering only.
__device__ __forceinline__ void lds_barrier() {
    asm volatile("s_waitcnt lgkmcnt(0)\n\ts_barrier" ::: "memory");
}

// ---------------------------------------------------------------------------
__global__ void prep_kernel(const float* __restrict__ wih,
                            const float* __restrict__ whh,
                            const float* __restrict__ bih,
                            const float* __restrict__ bhh,
                            u16* __restrict__ wihp, u16* __restrict__ whhp,
                            float* __restrict__ bias) {
    int n = blockIdx.x, k = threadIdx.x;
    bool v = (n < HID) && (k < HID);
    int src = n * HID + k, dst = n * KP + k;
    wihp[dst] = v ? f2bf(wih[src]) : (u16)0;
    whhp[dst] = v ? f2bf(whh[src]) : (u16)0;
    if (k == 0) bias[n] = (n < HID) ? (bih[n] + bhh[n]) : 0.0f;
}

// ---------------------------------------------------------------------------
// Phase 1 (R8): xp = in @ W_ih^T + bias. 2048 WGs x 512 thr.
// LDS: As[2] (A double-buf) + Bs[3] (B triple-buf, staged 2 ahead) = 76 KB.
__global__ __launch_bounds__(512, 1) void xproj_kernel(
    const float* __restrict__ in, const u16* __restrict__ wihp,
    const float* __restrict__ bias, u16* __restrict__ xp) {
    __shared__ __align__(16) u16 As[2][4096];
    __shared__ __align__(16) u16 Bs[3][10240];

    const int tid = threadIdx.x;
    const int w = tid >> 6, l = tid & 63;
    const int mi = w & 3, ni = w >> 2;
    const int l31 = l & 31, l5 = l >> 5;
    const int m0 = blockIdx.x * 128;

    const int sm = tid >> 2, skg = tid & 3;   // A staging: row, 8-k group

    f32x16 acc[5];
#pragma unroll
    for (int j = 0; j < 5; ++j)
#pragma unroll
        for (int r = 0; r < 16; ++r) acc[j][r] = 0.0f;

    const f32x4 zf = {0.f, 0.f, 0.f, 0.f};
    // Branchless A-load: always 2 VMEM ops (uniform vmcnt), clamp addr to
    // stay in-bounds, zero invalid k in registers.
    auto loadA = [&](int it, f32x4& v0, f32x4& v1) {
        int gk = it * 32 + skg * 8;
        int a0 = gk > 296 ? 296 : gk;
        int a1 = (gk + 4) > 296 ? 296 : (gk + 4);
        const float* p = in + (size_t)(m0 + sm) * HID;
        v0 = *(const f32x4*)(p + a0);
        v1 = *(const f32x4*)(p + a1);
        v0 = (gk > 296) ? zf : v0;        // gk>=304: fully padded
        v1 = ((gk + 4) > 296) ? zf : v1;  // k 300..303 -> 0
    };
    auto writeA = [&](int buf, const f32x4& v0, const f32x4& v1) {
        u32x4 pk;
        pk[0] = pack2(v0[0], v0[1]); pk[1] = pack2(v0[2], v0[3]);
        pk[2] = pack2(v1[0], v1[1]); pk[3] = pack2(v1[2], v1[3]);
        *(u32x4*)&As[buf][(skg >> 1) * 2048 + sm * 16 + (skg & 1) * 8] = pk;
    };
    auto stageB = [&](int buf, int it) {
#pragma unroll
        for (int s = 0; s < 3; ++s) {
            int i = w + 8 * s;                // wave-uniform predicate
            if (i < 20) {
                int c = i & 3, ng = i >> 2;
                int n = ng * 64 + l;
                const u16* g = wihp + n * KP + it * 32 + c * 8;
                u16* d = &Bs[buf][c * 2560 + ng * 512];
                __builtin_amdgcn_global_load_lds(
                    (const __attribute__((address_space(1))) void*)g,
                    (__attribute__((address_space(3))) void*)d, 16, 0, 0);
            }
        }
    };

    // Prologue: stage B for it=0 and it=1; A for it=0.
    {
        stageB(0, 0);
        f32x4 v0, v1;
        loadA(0, v0, v1);
        writeA(0, v0, v1);
        stageB(1, 1);
        asm volatile("s_waitcnt vmcnt(2)" ::: "memory");
        lds_barrier();
    }

    int cA = 0, cB = 0, sB = 2;
#pragma unroll 1
    for (int it = 0; it < 10; ++it) {
        f32x4 v0, v1;
        if (it < 9) loadA(it + 1, v0, v1);
        if (it < 8) stageB(sB, it + 2);
#pragma unroll
        for (int s = 0; s < 2; ++s) {
            bf16x8 a = *(const bf16x8*)&As[cA][s * 2048 + mi * 512 + l31 * 16 + l5 * 8];
#pragma unroll
            for (int j = 0; j < 5; ++j) {
                bf16x8 b = *(const bf16x8*)&Bs[cB][(s * 2 + l5) * 2560 + ((ni * 5 + j) * 32 + l31) * 8];
                acc[j] = __builtin_amdgcn_mfma_f32_32x32x16_bf16(a, b, acc[j], 0, 0, 0);
            }
        }
        if (it < 9) {
            writeA(cA ^ 1, v0, v1);
            if (it < 8) asm volatile("s_waitcnt vmcnt(3)" ::: "memory");
            else        asm volatile("s_waitcnt vmcnt(2)" ::: "memory");
            lds_barrier();
        }
        cA ^= 1;
        cB = (cB == 2) ? 0 : cB + 1;
        sB = (sB == 2) ? 0 : sB + 1;
    }

    const int mbase = m0 + mi * 32;
#pragma unroll
    for (int j = 0; j < 5; ++j) {
        int n = (ni * 5 + j) * 32 + l31;
        if (n < HID) {
            float bs = bias[n];
#pragma unroll
            for (int reg = 0; reg < 16; ++reg) {
                int row = (reg & 3) + 8 * (reg >> 2) + 4 * l5;
                xp[(size_t)(mbase + row) * HID + n] = f2bf(acc[j][reg] + bs);
            }
        }
    }
}

// ---------------------------------------------------------------------------
// Phase 2 (R10): recurrence. 32 WGs x 512 thr (8 waves, 2/SIMD), 16 batch/WG.
// Wave w owns N-tiles {w, w+8, w+16<only w<4>}. K split into L(ks0-4)/
// H(ks5-9) halves with separate accumulators; per-tile H chain is followed
// by that tile's tanh+write so tanh sinks under the next tile's MFMAs.
__global__ __launch_bounds__(512, 2) void rnn_recur_kernel(
    const u16* __restrict__ xp, const u16* __restrict__ whhp,
    float* __restrict__ out) {
    __shared__ __align__(16) u16 hb[2][16 * 328];   // double-buffered h

    const int tid = threadIdx.x;
    const int w = tid >> 6;            // wave 0..7
    const int l = tid & 63;
    const int br = l & 15;             // batch-rel (B col / C col)
    const int q  = l >> 4;             // quad
    const int b0 = blockIdx.x * 16;
    const bool t3 = (w < 4);           // waves 0-3 own a third tile

    // zero both h buffers (incl. padding)
    for (int i = tid; i < (2 * 16 * 328) / 2; i += 512) ((u32*)hb)[i] = 0;

    // W_hh A-fragments (load once; pinned to AGPRs)
    bf16x8 Af[3][10];
#pragma unroll
    for (int j = 0; j < 3; ++j) {
        if (j < 2 || t3) {
            const int nt = w + 8 * j;
            const u16* wrow = whhp + (size_t)(nt * 16 + br) * KP;
#pragma unroll
            for (int ks = 0; ks < 10; ++ks)
                Af[j][ks] = *(const bf16x8*)(wrow + ks * 32 + q * 8);
        }
    }
#pragma unroll
    for (int j = 0; j < 3; ++j)
        if (j < 2 || t3)
#pragma unroll
            for (int ks = 0; ks < 10; ++ks)
                asm volatile("" : "+a"(Af[j][ks]));

    // xp element offsets (step-invariant); -1 = fully-padded quad
    int xo[3];
#pragma unroll
    for (int j = 0; j < 3; ++j) {
        int n0 = (w + 8 * j) * 16 + q * 4;
        xo[j] = (n0 < HID && (j < 2 || t3)) ? ((b0 + br) * HID + n0) : -1;
    }

    const s16x4 z4 = {0, 0, 0, 0};
    s16x4 xc[3], xn[3];
#pragma unroll
    for (int j = 0; j < 3; ++j) {
        xc[j] = (xo[j] >= 0) ? *(const s16x4*)(xp + xo[j]) : z4;
        xn[j] = (xo[j] >= 0) ? *(const s16x4*)(xp + (size_t)BZ * HID + xo[j]) : z4;
    }

    lds_barrier();

#pragma unroll 1
    for (int t = 0; t < SEQ; ++t) {
        const u16* hc = hb[t & 1];
        u16*       hn = hb[(t + 1) & 1];

        // prefetch xp for t+2 (raw barrier keeps vmcnt free -> stays in flight)
        s16x4 xf[3];
        {
            int t2 = (t + 2 < SEQ) ? (t + 2) : (SEQ - 1);
            const u16* base = xp + (size_t)t2 * (BZ * HID);
#pragma unroll
            for (int j = 0; j < 3; ++j)
                xf[j] = (xo[j] >= 0) ? *(const s16x4*)(base + xo[j]) : z4;
        }

        // ---- L half: ks 0..4, accumulators seeded with xp (moves the
        // xc-add off the critical tail).
        bf16x8 bL[5];
#pragma unroll
        for (int ks = 0; ks < 5; ++ks)
            bL[ks] = *(const bf16x8*)&hc[br * 328 + ks * 32 + q * 8];

        f32x4 a0L, a1L, a2L;
#pragma unroll
        for (int r = 0; r < 4; ++r) {
            a0L[r] = bf2f((u16)xc[0][r]);
            a1L[r] = bf2f((u16)xc[1][r]);
            a2L[r] = bf2f((u16)xc[2][r]);
        }
#pragma unroll
        for (int ks = 0; ks < 5; ++ks) {
            a0L = __builtin_amdgcn_mfma_f32_16x16x32_bf16(Af[0][ks], bL[ks], a0L, 0, 0, 0);
            a1L = __builtin_amdgcn_mfma_f32_16x16x32_bf16(Af[1][ks], bL[ks], a1L, 0, 0, 0);
            if (t3)
                a2L = __builtin_amdgcn_mfma_f32_16x16x32_bf16(Af[2][ks], bL[ks], a2L, 0, 0, 0);
        }

        // ---- H half: ks 5..9, per-tile chain then that tile's epilogue.
        bf16x8 bH[5];
#pragma unroll
        for (int ks = 0; ks < 5; ++ks)
            bH[ks] = *(const bf16x8*)&hc[br * 328 + (ks + 5) * 32 + q * 8];

        f32x4 a0H, a1H, a2H;
#pragma unroll
        for (int r = 0; r < 4; ++r) { a0H[r] = 0.f; a1H[r] = 0.f; a2H[r] = 0.f; }

        // tile 0
#pragma unroll
        for (int ks = 0; ks < 5; ++ks)
            a0H = __builtin_amdgcn_mfma_f32_16x16x32_bf16(Af[0][ks + 5], bH[ks], a0H, 0, 0, 0);
        {
            int n0 = w * 16 + q * 4;
            u32x2 pk;
            pk[0] = pack2(tanh_fast(a0L[0] + a0H[0]), tanh_fast(a0L[1] + a0H[1]));
            pk[1] = pack2(tanh_fast(a0L[2] + a0H[2]), tanh_fast(a0L[3] + a0H[3]));
            *(u32x2*)&hn[br * 328 + n0] = pk;
        }

        // tile 1 (tanh0 sinks under these MFMAs)
#pragma unroll
        for (int ks = 0; ks < 5; ++ks)
            a1H = __builtin_amdgcn_mfma_f32_16x16x32_bf16(Af[1][ks + 5], bH[ks], a1H, 0, 0, 0);
        {
            int n0 = (w + 8) * 16 + q * 4;
            u32x2 pk;
            pk[0] = pack2(tanh_fast(a1L[0] + a1H[0]), tanh_fast(a1L[1] + a1H[1]));
            pk[1] = pack2(tanh_fast(a1L[2] + a1H[2]), tanh_fast(a1L[3] + a1H[3]));
            *(u32x2*)&hn[br * 328 + n0] = pk;
        }

        // tile 2 (waves 0-3 only; tanh1 sinks under these MFMAs)
        if (t3) {
#pragma unroll
            for (int ks = 0; ks < 5; ++ks)
                a2H = __builtin_amdgcn_mfma_f32_16x16x32_bf16(Af[2][ks + 5], bH[ks], a2H, 0, 0, 0);
            int n0 = (w + 16) * 16 + q * 4;
            u32x2 pk;
            pk[0] = pack2(tanh_fast(a2L[0] + a2H[0]), tanh_fast(a2L[1] + a2H[1]));
            pk[1] = pack2(tanh_fast(a2L[2] + a2H[2]), tanh_fast(a2L[3] + a2H[3]));
            *(u32x2*)&hn[br * 328 + n0] = pk;
        }

        lds_barrier();   // LDS-only ordering; xp loads stay in flight

#pragma unroll
        for (int j = 0; j < 3; ++j) { xc[j] = xn[j]; xn[j] = xf[j]; }
    }

    // final h_512 lives in hb[0] (512 even)
    const u16* hf = hb[0];
    for (int i = tid; i < 16 * HID; i += 512) {
        int r = i / HID, n = i - r * HID;
        out[(size_t)(b0 + r) * HID + n] = bf2f(hf[r * 328 + n]);
    }
}

// ---------------------------------------------------------------------------
extern "C" void kernel_launch(void* const* d_in, const int* in_sizes, int n_in,
                              void* d_out, int out_size, void* d_ws, size_t ws_size,
                              hipStream_t stream) {
    const float* in  = (const float*)d_in[0];
    const float* wih = (const float*)d_in[1];
    const float* whh = (const float*)d_in[2];
    const float* bih = (const float*)d_in[3];
    const float* bhh = (const float*)d_in[4];

    char* ws = (char*)d_ws;
    const size_t XP_BYTES = (size_t)MTOT * HID * sizeof(u16);   // 157,286,400
    u16*   xpb  = (u16*)ws;
    u16*   wihp = (u16*)(ws + XP_BYTES);
    u16*   whhp = (u16*)(ws + XP_BYTES + (size_t)KP * KP * 2);
    float* bias = (float*)(ws + XP_BYTES + 2 * (size_t)KP * KP * 2);

    prep_kernel<<<KP, KP, 0, stream>>>(wih, whh, bih, bhh, wihp, whhp, bias);
    xproj_kernel<<<MTOT / 128, 512, 0, stream>>>(in, wihp, bias, xpb);
    rnn_recur_kernel<<<BZ / 16, 512, 0, stream>>>(xpb, whhp, (float*)d_out);
}